// Round 1
// baseline (143.023 us; speedup 1.0000x reference)
//
#include <hip/hip_runtime.h>
#include <math.h>

#define BATCH 1024
#define DIM 128
#define NEG_OFF 100000.0f
#define EPSV 1e-12f
#define MARGIN 0.5f
#define INTRA_MARGIN 0.1f
#define LAMDA 0.5f

// One block per (half, row). 2048 blocks x 256 threads.
__global__ __launch_bounds__(256) void bidir_row_kernel(
    const float* __restrict__ feat,
    const int* __restrict__ label1,
    const int* __restrict__ label2,
    float* __restrict__ partial)
{
    const int bid  = blockIdx.x;        // 0..2047
    const int half = bid >> 10;         // 0: f1 vs f2 ; 1: f2 vs f1
    const int i    = bid & (BATCH - 1);
    const int t    = threadIdx.x;

    const float* fa = feat + (half ? BATCH * DIM : 0);
    const float* fb = feat + (half ? 0 : BATCH * DIM);   // also f_intra
    const int* la = half ? label2 : label1;
    const int* lb = half ? label1 : label2;

    __shared__ float4 a4[DIM / 4];      // row vector a, broadcast-read
    if (t < DIM / 4)
        a4[t] = reinterpret_cast<const float4*>(fa + i * DIM)[t];
    __syncthreads();

    const int lab_i = la[i];

    // per-thread best positive (max, first idx) / best negative (min, first idx)
    float bpv = -1.0f; int bpj = 0x7fffffff;
    float bnv = 3.4e38f; int bnj = 0x7fffffff;

    #pragma unroll
    for (int q = 0; q < 4; ++q) {
        const int j = q * 256 + t;       // j increasing within thread
        const float4* brow = reinterpret_cast<const float4*>(fb + j * DIM);
        float d2 = 0.0f;
        #pragma unroll
        for (int k = 0; k < DIM / 4; ++k) {
            float4 b = brow[k];
            float4 a = a4[k];
            float dx = a.x - b.x, dy = a.y - b.y, dz = a.z - b.z, dw = a.w - b.w;
            d2 += dx * dx + dy * dy + dz * dz + dw * dw;
        }
        const float dist = sqrtf(d2 + EPSV);
        const bool same = (lb[j] == lab_i);
        const float pv = same ? dist : 0.0f;          // dis * s
        const float nv = dist + (same ? NEG_OFF : 0.0f);
        if (pv > bpv) { bpv = pv; bpj = j; }          // strict > : first occurrence
        if (nv < bnv) { bnv = nv; bnj = j; }          // strict < : first occurrence
    }

    __shared__ float s_pv[256]; __shared__ int s_pj[256];
    __shared__ float s_nv[256]; __shared__ int s_nj[256];
    s_pv[t] = bpv; s_pj[t] = bpj;
    s_nv[t] = bnv; s_nj[t] = bnj;
    __syncthreads();

    // tree reduce with first-occurrence tie-break (smaller j wins on equal value)
    for (int s = 128; s > 0; s >>= 1) {
        if (t < s) {
            float ov = s_pv[t + s]; int oj = s_pj[t + s];
            if (ov > s_pv[t] || (ov == s_pv[t] && oj < s_pj[t])) { s_pv[t] = ov; s_pj[t] = oj; }
            float wv = s_nv[t + s]; int wj = s_nj[t + s];
            if (wv < s_nv[t] || (wv == s_nv[t] && wj < s_nj[t])) { s_nv[t] = wv; s_nj[t] = wj; }
        }
        __syncthreads();
    }

    // gathered intra distance: dist(f_intra[pp], f_intra[pn]) over 128 dims, wave 0
    if (t < 64) {
        const int pp = s_pj[0];
        const int pn = s_nj[0];
        const float* x = fb + pp * DIM;
        const float* y = fb + pn * DIM;
        float dx0 = x[2 * t]     - y[2 * t];
        float dx1 = x[2 * t + 1] - y[2 * t + 1];
        float d2 = dx0 * dx0 + dx1 * dx1;
        #pragma unroll
        for (int off = 32; off > 0; off >>= 1)
            d2 += __shfl_down(d2, off);
        if (t == 0) {
            const float g = sqrtf(d2 + EPSV);
            const float fp = s_pv[0];
            const float cn = s_nv[0];
            const float cross = fmaxf(fp - cn + MARGIN, 0.0f);
            const float intra = fmaxf(INTRA_MARGIN - g, 0.0f);
            partial[bid] = (cross + LAMDA * intra) * (1.0f / (float)BATCH);
        }
    }
}

// Deterministic final reduction of 2048 partials -> scalar
__global__ __launch_bounds__(256) void bidir_reduce_kernel(
    const float* __restrict__ partial, float* __restrict__ out)
{
    const int t = threadIdx.x;
    float s = 0.0f;
    #pragma unroll
    for (int k = 0; k < 8; ++k)
        s += partial[t + 256 * k];
    #pragma unroll
    for (int off = 32; off > 0; off >>= 1)
        s += __shfl_down(s, off);
    __shared__ float ws[4];
    if ((t & 63) == 0) ws[t >> 6] = s;
    __syncthreads();
    if (t == 0) out[0] = ws[0] + ws[1] + ws[2] + ws[3];
}

extern "C" void kernel_launch(void* const* d_in, const int* in_sizes, int n_in,
                              void* d_out, int out_size, void* d_ws, size_t ws_size,
                              hipStream_t stream) {
    const float* feat   = (const float*)d_in[0];
    const int*   label1 = (const int*)d_in[1];
    const int*   label2 = (const int*)d_in[2];
    float* out     = (float*)d_out;
    float* partial = (float*)d_ws;   // 2048 floats = 8 KB

    bidir_row_kernel<<<dim3(2 * BATCH), dim3(256), 0, stream>>>(feat, label1, label2, partial);
    bidir_reduce_kernel<<<dim3(1), dim3(256), 0, stream>>>(partial, out);
}

// Round 2
// 33.755 us; speedup vs baseline: 4.2371x; 4.2371x over previous
//
#include <hip/hip_runtime.h>
#include <math.h>
#include <float.h>

#define BATCH 1024
#define DIM 128
#define NEG_OFF 100000.0f
#define EPSV 1e-12f
#define MARGIN 0.5f
#define INTRA_MARGIN 0.1f
#define LAMDA 0.5f

#define R 8          // rows per block
#define T 512        // threads per block (8 waves)
#define NBLK (2 * BATCH / R)   // 256 blocks

// Each block: 8 rows of one half vs all 1024 columns of the other half.
// Thread t owns columns {t, t+512}; 8x2 register tile of squared distances.
__global__ __launch_bounds__(T) void bidir_tile_kernel(
    const float* __restrict__ feat,
    const int* __restrict__ label1,
    const int* __restrict__ label2,
    float* __restrict__ partial)
{
    const int bid      = blockIdx.x;          // 0..255
    const int half     = bid >> 7;            // 128 blocks per half
    const int row_base = (bid & 127) * R;
    const int t        = threadIdx.x;

    const float* fa = feat + (half ? BATCH * DIM : 0);
    const float* fb = feat + (half ? 0 : BATCH * DIM);   // also f_intra
    const int* la = half ? label2 : label1;
    const int* lb = half ? label1 : label2;

    __shared__ float4 aT[R * DIM / 4];        // 8 rows x 128 floats = 4 KB
    if (t < R * DIM / 4)
        aT[t] = reinterpret_cast<const float4*>(fa + row_base * DIM)[t];

    int lab_a[R];
    #pragma unroll
    for (int r = 0; r < R; ++r) lab_a[r] = la[row_base + r];

    __syncthreads();

    // ---- 8x2 register tile of squared distances over K=128 ----
    float acc[R][2];
    #pragma unroll
    for (int r = 0; r < R; ++r) { acc[r][0] = 0.0f; acc[r][1] = 0.0f; }

    const float4* b0 = reinterpret_cast<const float4*>(fb + (size_t)t * DIM);
    const float4* b1 = reinterpret_cast<const float4*>(fb + (size_t)(t + T) * DIM);

    #pragma unroll 4
    for (int k = 0; k < DIM / 4; ++k) {
        const float4 x0 = b0[k];
        const float4 x1 = b1[k];
        #pragma unroll
        for (int r = 0; r < R; ++r) {
            const float4 a = aT[(r << 5) + k];
            float d;
            d = a.x - x0.x; acc[r][0] = fmaf(d, d, acc[r][0]);
            d = a.y - x0.y; acc[r][0] = fmaf(d, d, acc[r][0]);
            d = a.z - x0.z; acc[r][0] = fmaf(d, d, acc[r][0]);
            d = a.w - x0.w; acc[r][0] = fmaf(d, d, acc[r][0]);
            d = a.x - x1.x; acc[r][1] = fmaf(d, d, acc[r][1]);
            d = a.y - x1.y; acc[r][1] = fmaf(d, d, acc[r][1]);
            d = a.z - x1.z; acc[r][1] = fmaf(d, d, acc[r][1]);
            d = a.w - x1.w; acc[r][1] = fmaf(d, d, acc[r][1]);
        }
    }

    // ---- selection in d^2 domain (sqrt is monotonic) ----
    // positive candidate: same ? d2 : 0   (matches dis*s ordering; no-positive -> all 0 -> idx 0)
    // negative candidate: same ? FLT_MAX : d2  (offset only needs to exceed all real d2)
    const int lb0 = lb[t];
    const int lb1 = lb[t + T];

    float bpv[R]; int bpj[R]; float bnv[R]; int bnj[R];
    #pragma unroll
    for (int r = 0; r < R; ++r) {
        const bool s0 = (lb0 == lab_a[r]);
        bpv[r] = s0 ? acc[r][0] : 0.0f;
        bnv[r] = s0 ? FLT_MAX : acc[r][0];
        bpj[r] = t; bnj[r] = t;
        const bool s1 = (lb1 == lab_a[r]);
        const float pv1 = s1 ? acc[r][1] : 0.0f;
        const float nv1 = s1 ? FLT_MAX : acc[r][1];
        // j1 = t+T > j0 always: tie keeps earlier index -> strict compares only
        if (pv1 > bpv[r]) { bpv[r] = pv1; bpj[r] = t + T; }
        if (nv1 < bnv[r]) { bnv[r] = nv1; bnj[r] = t + T; }
    }

    // ---- in-wave butterfly reduce (value, first-occurrence index) ----
    #pragma unroll
    for (int r = 0; r < R; ++r) {
        #pragma unroll
        for (int off = 32; off > 0; off >>= 1) {
            const float opv = __shfl_xor(bpv[r], off);
            const int   opj = __shfl_xor(bpj[r], off);
            if (opv > bpv[r] || (opv == bpv[r] && opj < bpj[r])) { bpv[r] = opv; bpj[r] = opj; }
            const float onv = __shfl_xor(bnv[r], off);
            const int   onj = __shfl_xor(bnj[r], off);
            if (onv < bnv[r] || (onv == bnv[r] && onj < bnj[r])) { bnv[r] = onv; bnj[r] = onj; }
        }
    }

    // ---- cross-wave combine: 8 waves x 8 rows ----
    __shared__ float w_pv[R][8]; __shared__ int w_pj[R][8];
    __shared__ float w_nv[R][8]; __shared__ int w_nj[R][8];
    if ((t & 63) == 0) {
        const int w = t >> 6;
        #pragma unroll
        for (int r = 0; r < R; ++r) {
            w_pv[r][w] = bpv[r]; w_pj[r][w] = bpj[r];
            w_nv[r][w] = bnv[r]; w_nj[r][w] = bnj[r];
        }
    }
    __syncthreads();

    __shared__ int s_pp[R], s_pn[R];
    __shared__ float s_fp[R], s_cn[R];
    if (t < R) {
        float pv = -1.0f; int pj = 0x7fffffff;
        float nv = FLT_MAX; int nj = 0x7fffffff;
        #pragma unroll
        for (int w = 0; w < 8; ++w) {
            const float v1 = w_pv[t][w]; const int j1 = w_pj[t][w];
            if (v1 > pv || (v1 == pv && j1 < pj)) { pv = v1; pj = j1; }
            const float v2 = w_nv[t][w]; const int j2 = w_nj[t][w];
            if (v2 < nv || (v2 == nv && j2 < nj)) { nv = v2; nj = j2; }
        }
        s_pp[t] = pj;
        s_pn[t] = nj;
        s_fp[t] = (pv > 0.0f) ? sqrtf(pv + EPSV) : 0.0f;   // no-positive row -> fp = 0
        s_cn[t] = sqrtf(nv + EPSV);                        // no-negative -> huge -> cross = 0
    }
    __syncthreads();

    // ---- intra distances: 8 groups of 32 lanes, one row each ----
    __shared__ float s_res[R];
    if (t < 256) {
        const int g = t >> 5, l = t & 31;
        const float* x = fb + (size_t)s_pp[g] * DIM;
        const float* y = fb + (size_t)s_pn[g] * DIM;
        const float4 xv = reinterpret_cast<const float4*>(x)[l];
        const float4 yv = reinterpret_cast<const float4*>(y)[l];
        float d, d2;
        d = xv.x - yv.x; d2  = d * d;
        d = xv.y - yv.y; d2 += d * d;
        d = xv.z - yv.z; d2 += d * d;
        d = xv.w - yv.w; d2 += d * d;
        #pragma unroll
        for (int off = 16; off > 0; off >>= 1)
            d2 += __shfl_down(d2, off, 32);
        if (l == 0) {
            const float gd    = sqrtf(d2 + EPSV);
            const float cross = fmaxf(s_fp[g] - s_cn[g] + MARGIN, 0.0f);
            const float intra = fmaxf(INTRA_MARGIN - gd, 0.0f);
            s_res[g] = (cross + LAMDA * intra) * (1.0f / (float)BATCH);
        }
    }
    __syncthreads();
    if (t == 0) {
        float s = 0.0f;
        #pragma unroll
        for (int r = 0; r < R; ++r) s += s_res[r];
        partial[bid] = s;
    }
}

// Deterministic final reduction of 256 partials -> scalar
__global__ __launch_bounds__(256) void bidir_reduce_kernel(
    const float* __restrict__ partial, float* __restrict__ out)
{
    const int t = threadIdx.x;
    float s = partial[t];
    #pragma unroll
    for (int off = 32; off > 0; off >>= 1)
        s += __shfl_down(s, off);
    __shared__ float ws[4];
    if ((t & 63) == 0) ws[t >> 6] = s;
    __syncthreads();
    if (t == 0) out[0] = ws[0] + ws[1] + ws[2] + ws[3];
}

extern "C" void kernel_launch(void* const* d_in, const int* in_sizes, int n_in,
                              void* d_out, int out_size, void* d_ws, size_t ws_size,
                              hipStream_t stream) {
    const float* feat   = (const float*)d_in[0];
    const int*   label1 = (const int*)d_in[1];
    const int*   label2 = (const int*)d_in[2];
    float* out     = (float*)d_out;
    float* partial = (float*)d_ws;   // 256 floats = 1 KB

    bidir_tile_kernel<<<dim3(NBLK), dim3(T), 0, stream>>>(feat, label1, label2, partial);
    bidir_reduce_kernel<<<dim3(1), dim3(256), 0, stream>>>(partial, out);
}

// Round 3
// 31.031 us; speedup vs baseline: 4.6090x; 1.0878x over previous
//
#include <hip/hip_runtime.h>
#include <math.h>
#include <float.h>

#define BATCH 1024
#define DIM 128
#define EPSV 1e-12f
#define MARGIN 0.5f
#define INTRA_MARGIN 0.1f
#define LAMDA 0.5f

typedef __attribute__((ext_vector_type(8))) short s16x8;   // 8 bf16 (4 VGPRs)
typedef __attribute__((ext_vector_type(4))) float f32x4;   // MFMA C/D

__device__ __forceinline__ ushort f2bf(float f) {          // RNE fp32 -> bf16
    unsigned u = __float_as_uint(f);
    return (ushort)((u + 0x7fffu + ((u >> 16) & 1u)) >> 16);
}
__device__ __forceinline__ float bf2f(ushort h) { return __uint_as_float(((unsigned)h) << 16); }

// ---------------- Kernel A: convert feat -> bf16 hi/lo + fp32 row norms ----------------
// 128 blocks x 256 threads; 16 threads per row, 8 floats per thread.
__global__ __launch_bounds__(256) void prep_kernel(
    const float* __restrict__ feat, ushort* __restrict__ bhi,
    ushort* __restrict__ blo, float* __restrict__ norm2)
{
    const int gt  = blockIdx.x * 256 + threadIdx.x;   // 0..32767
    const int row = gt >> 4, seg = gt & 15;
    const float4* p = reinterpret_cast<const float4*>(feat + (size_t)row * DIM + seg * 8);
    const float4 a = p[0], b = p[1];
    const float v[8] = {a.x, a.y, a.z, a.w, b.x, b.y, b.z, b.w};
    ushort h[8], l[8];
    float n = 0.0f;
    #pragma unroll
    for (int e = 0; e < 8; ++e) {
        const float f  = v[e];
        const ushort hb = f2bf(f);
        h[e] = hb;
        l[e] = f2bf(f - bf2f(hb));
        n = fmaf(f, f, n);
    }
    uint4 uh, ul;
    uh.x = (uint)h[0] | ((uint)h[1] << 16); uh.y = (uint)h[2] | ((uint)h[3] << 16);
    uh.z = (uint)h[4] | ((uint)h[5] << 16); uh.w = (uint)h[6] | ((uint)h[7] << 16);
    ul.x = (uint)l[0] | ((uint)l[1] << 16); ul.y = (uint)l[2] | ((uint)l[3] << 16);
    ul.z = (uint)l[4] | ((uint)l[5] << 16); ul.w = (uint)l[6] | ((uint)l[7] << 16);
    *reinterpret_cast<uint4*>(bhi + (size_t)row * DIM + seg * 8) = uh;
    *reinterpret_cast<uint4*>(blo + (size_t)row * DIM + seg * 8) = ul;
    n += __shfl_xor(n, 1); n += __shfl_xor(n, 2);
    n += __shfl_xor(n, 4); n += __shfl_xor(n, 8);
    if ((threadIdx.x & 15) == 0) norm2[row] = n;
}

// ---------------- Kernel B: MFMA gram + online selection ----------------
// 256 blocks (64 rowblocks x 4 colchunks) x 512 threads (8 waves).
// Block: 32 rows x 256 cols. Wave w: rowtile=w>>2 (16 rows), coltile=w&3 (64 cols = 4 subtiles of 16).
__global__ __launch_bounds__(512) void gemm_select_kernel(
    const ushort* __restrict__ bhi, const ushort* __restrict__ blo,
    const float* __restrict__ norm2,
    const int* __restrict__ label1, const int* __restrict__ label2,
    float4* __restrict__ cand)
{
    const int rowblk = blockIdx.x >> 2;
    const int chunk  = blockIdx.x & 3;
    const int half   = rowblk >> 5;
    const int arow0  = (rowblk & 31) * 32;            // row base within half
    const int aglob0 = half * BATCH + arow0;          // row base in 2048-row arrays
    const int bglob0 = (half ^ 1) * BATCH;            // b-side base
    const int col0   = chunk * 256;

    const int t = threadIdx.x;
    const int w = t >> 6, lane = t & 63;
    const int rowtile = w >> 2, coltile = w & 3;
    const int l15 = lane & 15, kg = lane >> 4;

    const int* labA = half ? label2 : label1;
    const int* labB = half ? label1 : label2;

    // A-operand row, B cols for the 4 subtiles
    const int a_glob = aglob0 + rowtile * 16 + l15;
    int jcol[4]; float nb[4]; int lb[4]; size_t bbase[4];
    #pragma unroll
    for (int s = 0; s < 4; ++s) {
        jcol[s]  = col0 + coltile * 64 + s * 16 + l15;
        const int bg = bglob0 + jcol[s];
        bbase[s] = (size_t)bg * DIM;
        nb[s] = norm2[bg];
        lb[s] = labB[jcol[s]];
    }

    f32x4 acc[4];
    #pragma unroll
    for (int s = 0; s < 4; ++s) acc[s] = (f32x4){0.f, 0.f, 0.f, 0.f};

    const size_t abase = (size_t)a_glob * DIM;
    #pragma unroll
    for (int kt = 0; kt < 4; ++kt) {
        const int koff = kt * 32 + kg * 8;
        const s16x8 ah = *reinterpret_cast<const s16x8*>(bhi + abase + koff);
        const s16x8 al = *reinterpret_cast<const s16x8*>(blo + abase + koff);
        s16x8 bh[4], bl[4];
        #pragma unroll
        for (int s = 0; s < 4; ++s) {
            bh[s] = *reinterpret_cast<const s16x8*>(bhi + bbase[s] + koff);
            bl[s] = *reinterpret_cast<const s16x8*>(blo + bbase[s] + koff);
        }
        #pragma unroll
        for (int s = 0; s < 4; ++s) {
            acc[s] = __builtin_amdgcn_mfma_f32_16x16x32_bf16(ah, bh[s], acc[s], 0, 0, 0);
            acc[s] = __builtin_amdgcn_mfma_f32_16x16x32_bf16(ah, bl[s], acc[s], 0, 0, 0);
            acc[s] = __builtin_amdgcn_mfma_f32_16x16x32_bf16(al, bh[s], acc[s], 0, 0, 0);
        }
    }

    // C/D layout: col = l15 (matches jcol), row = kg*4 + reg (verified m89/m91)
    const int arow_c  = aglob0 + rowtile * 16 + kg * 4;
    const int arow_ih = arow0  + rowtile * 16 + kg * 4;
    float na[4]; int la[4];
    #pragma unroll
    for (int r = 0; r < 4; ++r) { na[r] = norm2[arow_c + r]; la[r] = labA[arow_ih + r]; }

    float bpv[4], bnv[4]; int bpj[4], bnj[4];
    #pragma unroll
    for (int r = 0; r < 4; ++r) { bpv[r] = -1.0f; bpj[r] = 0x7fffffff; bnv[r] = FLT_MAX; bnj[r] = 0x7fffffff; }

    #pragma unroll
    for (int s = 0; s < 4; ++s) {
        #pragma unroll
        for (int r = 0; r < 4; ++r) {
            const float d2 = fmaxf(na[r] + nb[s] - 2.0f * acc[s][r], 0.0f);
            const bool same = (la[r] == lb[s]);
            const float pv = same ? d2 : 0.0f;
            const float nv = same ? FLT_MAX : d2;
            // j ascending over s within a lane -> strict compares keep first occurrence
            if (pv > bpv[r]) { bpv[r] = pv; bpj[r] = jcol[s]; }
            if (nv < bnv[r]) { bnv[r] = nv; bnj[r] = jcol[s]; }
        }
    }

    // reduce over the 16 lanes of each row group (masks 1..8 stay within 16-lane groups)
    #pragma unroll
    for (int r = 0; r < 4; ++r) {
        #pragma unroll
        for (int m = 8; m > 0; m >>= 1) {
            const float opv = __shfl_xor(bpv[r], m); const int opj = __shfl_xor(bpj[r], m);
            if (opv > bpv[r] || (opv == bpv[r] && opj < bpj[r])) { bpv[r] = opv; bpj[r] = opj; }
            const float onv = __shfl_xor(bnv[r], m); const int onj = __shfl_xor(bnj[r], m);
            if (onv < bnv[r] || (onv == bnv[r] && onj < bnj[r])) { bnv[r] = onv; bnj[r] = onj; }
        }
    }

    __shared__ float L_pv[32][4]; __shared__ int L_pj[32][4];
    __shared__ float L_nv[32][4]; __shared__ int L_nj[32][4];
    if (l15 == 0) {
        #pragma unroll
        for (int r = 0; r < 4; ++r) {
            const int rib = rowtile * 16 + kg * 4 + r;
            L_pv[rib][coltile] = bpv[r]; L_pj[rib][coltile] = bpj[r];
            L_nv[rib][coltile] = bnv[r]; L_nj[rib][coltile] = bnj[r];
        }
    }
    __syncthreads();

    if (t < 32) {
        float pv = -1.0f; int pj = 0x7fffffff; float nv = FLT_MAX; int nj = 0x7fffffff;
        #pragma unroll
        for (int c = 0; c < 4; ++c) {   // ascending col ranges -> strict + tie keeps first
            const float v1 = L_pv[t][c]; const int j1 = L_pj[t][c];
            if (v1 > pv || (v1 == pv && j1 < pj)) { pv = v1; pj = j1; }
            const float v2 = L_nv[t][c]; const int j2 = L_nj[t][c];
            if (v2 < nv || (v2 == nv && j2 < nj)) { nv = v2; nj = j2; }
        }
        cand[(size_t)(aglob0 + t) * 4 + chunk] =
            make_float4(pv, __int_as_float(pj), nv, __int_as_float(nj));
    }
}

// ---------------- Kernel C: combine chunks + exact intra gather ----------------
// 128 blocks x 256 threads; 16 lanes per row, 16 rows per block.
__global__ __launch_bounds__(256) void finalize_kernel(
    const float* __restrict__ feat, const float4* __restrict__ cand,
    float* __restrict__ partial)
{
    const int t  = threadIdx.x;
    const int gr = blockIdx.x * 16 + (t >> 4);
    const int sl = t & 15;
    const int half = gr >> 10;
    const float* fb = feat + (half ? 0 : BATCH * DIM);   // b-side features = f_intra

    float pv = -1.0f; int pj = 0x7fffffff; float nv = FLT_MAX; int nj = 0x7fffffff;
    #pragma unroll
    for (int c = 0; c < 4; ++c) {
        const float4 e = cand[(size_t)gr * 4 + c];
        const int ej = __float_as_int(e.y), en = __float_as_int(e.w);
        if (e.x > pv || (e.x == pv && ej < pj)) { pv = e.x; pj = ej; }
        if (e.z < nv || (e.z == nv && en < nj)) { nv = e.z; nj = en; }
    }
    pj = pj > (BATCH - 1) ? (BATCH - 1) : pj;   // safety (unreachable in practice)
    nj = nj > (BATCH - 1) ? (BATCH - 1) : nj;
    const float fp = (pv > 0.0f) ? sqrtf(pv + EPSV) : 0.0f;  // no-positive row -> 0
    const float cn = sqrtf(nv + EPSV);                       // no-negative -> huge -> cross 0

    const float4* x = reinterpret_cast<const float4*>(fb + (size_t)pj * DIM + sl * 8);
    const float4* y = reinterpret_cast<const float4*>(fb + (size_t)nj * DIM + sl * 8);
    const float4 x0 = x[0], x1 = x[1], y0 = y[0], y1 = y[1];
    float d, d2;
    d = x0.x - y0.x; d2  = d * d;  d = x0.y - y0.y; d2 += d * d;
    d = x0.z - y0.z; d2 += d * d;  d = x0.w - y0.w; d2 += d * d;
    d = x1.x - y1.x; d2 += d * d;  d = x1.y - y1.y; d2 += d * d;
    d = x1.z - y1.z; d2 += d * d;  d = x1.w - y1.w; d2 += d * d;
    d2 += __shfl_xor(d2, 1); d2 += __shfl_xor(d2, 2);
    d2 += __shfl_xor(d2, 4); d2 += __shfl_xor(d2, 8);

    __shared__ float ls[16];
    if (sl == 0) {
        const float g = sqrtf(d2 + EPSV);
        const float loss = fmaxf(fp - cn + MARGIN, 0.0f) + LAMDA * fmaxf(INTRA_MARGIN - g, 0.0f);
        ls[t >> 4] = loss * (1.0f / (float)BATCH);
    }
    __syncthreads();
    if (t == 0) {
        float s = 0.0f;
        #pragma unroll
        for (int i = 0; i < 16; ++i) s += ls[i];
        partial[blockIdx.x] = s;
    }
}

// ---------------- Kernel D: final reduce (128 partials) ----------------
__global__ __launch_bounds__(128) void reduce_kernel(
    const float* __restrict__ partial, float* __restrict__ out)
{
    const int t = threadIdx.x;
    float s = partial[t];
    #pragma unroll
    for (int m = 32; m > 0; m >>= 1) s += __shfl_down(s, m);
    __shared__ float ws2[2];
    if ((t & 63) == 0) ws2[t >> 6] = s;
    __syncthreads();
    if (t == 0) out[0] = ws2[0] + ws2[1];
}

extern "C" void kernel_launch(void* const* d_in, const int* in_sizes, int n_in,
                              void* d_out, int out_size, void* d_ws, size_t ws_size,
                              hipStream_t stream) {
    const float* feat   = (const float*)d_in[0];
    const int*   label1 = (const int*)d_in[1];
    const int*   label2 = (const int*)d_in[2];
    float* out = (float*)d_out;

    char* ws = (char*)d_ws;
    ushort* bhi    = (ushort*)(ws);                          // 512 KB
    ushort* blo    = (ushort*)(ws + 512 * 1024);             // 512 KB
    float*  norm2  = (float*)(ws + 1024 * 1024);             // 8 KB (pad to 16)
    float4* cand   = (float4*)(ws + 1024 * 1024 + 16384);    // 128 KB
    float*  part   = (float*)(ws + 1024 * 1024 + 16384 + 131072);

    prep_kernel<<<dim3(128), dim3(256), 0, stream>>>(feat, bhi, blo, norm2);
    gemm_select_kernel<<<dim3(256), dim3(512), 0, stream>>>(bhi, blo, norm2, label1, label2, cand);
    finalize_kernel<<<dim3(128), dim3(256), 0, stream>>>(feat, cand, part);
    reduce_kernel<<<dim3(1), dim3(128), 0, stream>>>(part, out);
}

// Round 4
// 30.215 us; speedup vs baseline: 4.7336x; 1.0270x over previous
//
#include <hip/hip_runtime.h>
#include <math.h>
#include <float.h>

#define BATCH 1024
#define DIM 128
#define EPSV 1e-12f
#define MARGIN 0.5f
#define INTRA_MARGIN 0.1f
#define LAMDA 0.5f

typedef __attribute__((ext_vector_type(8))) short s16x8;   // 8 bf16 (4 VGPRs)
typedef __attribute__((ext_vector_type(4))) float f32x4;   // MFMA C/D

__device__ __forceinline__ ushort f2bf(float f) {          // RNE fp32 -> bf16
    unsigned u = __float_as_uint(f);
    return (ushort)((u + 0x7fffu + ((u >> 16) & 1u)) >> 16);
}

// ---------------- Kernel A: feat -> bf16 + fp32 row norms + counter reset ----------------
// 128 blocks x 256 threads; 16 threads per row, 8 floats per thread.
__global__ __launch_bounds__(256) void prep_kernel(
    const float* __restrict__ feat, ushort* __restrict__ bhi,
    float* __restrict__ norm2, unsigned int* __restrict__ counter)
{
    if (blockIdx.x == 0 && threadIdx.x == 0) counter[0] = 0u;

    const int gt  = blockIdx.x * 256 + threadIdx.x;   // 0..32767
    const int row = gt >> 4, seg = gt & 15;
    const float4* p = reinterpret_cast<const float4*>(feat + (size_t)row * DIM + seg * 8);
    const float4 a = p[0], b = p[1];
    const float v[8] = {a.x, a.y, a.z, a.w, b.x, b.y, b.z, b.w};
    ushort h[8];
    float n = 0.0f;
    #pragma unroll
    for (int e = 0; e < 8; ++e) {
        h[e] = f2bf(v[e]);
        n = fmaf(v[e], v[e], n);
    }
    uint4 uh;
    uh.x = (uint)h[0] | ((uint)h[1] << 16); uh.y = (uint)h[2] | ((uint)h[3] << 16);
    uh.z = (uint)h[4] | ((uint)h[5] << 16); uh.w = (uint)h[6] | ((uint)h[7] << 16);
    *reinterpret_cast<uint4*>(bhi + (size_t)row * DIM + seg * 8) = uh;
    n += __shfl_xor(n, 1); n += __shfl_xor(n, 2);
    n += __shfl_xor(n, 4); n += __shfl_xor(n, 8);
    if ((threadIdx.x & 15) == 0) norm2[row] = n;
}

// ---------------- Kernel B: MFMA gram + selection + intra + full reduce ----------------
// 128 blocks x 512 threads. Block = 16 rows (one half) x ALL 1024 cols (other half).
// Wave w covers cols [w*128, w*128+128) as 8 subtiles of 16.
__global__ __launch_bounds__(512) void gemm_finalize_kernel(
    const ushort* __restrict__ bhi, const float* __restrict__ norm2,
    const float* __restrict__ feat,
    const int* __restrict__ label1, const int* __restrict__ label2,
    float* __restrict__ partial, unsigned int* __restrict__ counter,
    float* __restrict__ out)
{
    const int bid    = blockIdx.x;
    const int half   = bid >> 6;                 // 64 blocks per half
    const int arow0  = (bid & 63) * 16;          // row base within half
    const int aglob0 = half * BATCH + arow0;     // row base in 2048-row arrays
    const int bglob0 = (half ^ 1) * BATCH;

    const int t = threadIdx.x;
    const int w = t >> 6, lane = t & 63;
    const int l15 = lane & 15, kg = lane >> 4;

    const int* labA = half ? label2 : label1;
    const int* labB = half ? label1 : label2;

    // ---- operand setup ----
    const size_t abase = (size_t)(aglob0 + l15) * DIM;
    int jcol[8]; float nb[8]; int lb[8]; size_t bbase[8];
    #pragma unroll
    for (int s = 0; s < 8; ++s) {
        jcol[s]  = w * 128 + s * 16 + l15;
        const int bg = bglob0 + jcol[s];
        bbase[s] = (size_t)bg * DIM;
        nb[s] = norm2[bg];
        lb[s] = labB[jcol[s]];
    }

    f32x4 acc[8];
    #pragma unroll
    for (int s = 0; s < 8; ++s) acc[s] = (f32x4){0.f, 0.f, 0.f, 0.f};

    #pragma unroll
    for (int kt = 0; kt < 4; ++kt) {
        const int koff = kt * 32 + kg * 8;
        const s16x8 ah = *reinterpret_cast<const s16x8*>(bhi + abase + koff);
        #pragma unroll
        for (int s = 0; s < 8; ++s) {
            const s16x8 bh = *reinterpret_cast<const s16x8*>(bhi + bbase[s] + koff);
            acc[s] = __builtin_amdgcn_mfma_f32_16x16x32_bf16(ah, bh, acc[s], 0, 0, 0);
        }
    }

    // ---- selection in d^2 domain; C/D layout: col=l15, row=kg*4+reg ----
    float na[4]; int la[4];
    #pragma unroll
    for (int r = 0; r < 4; ++r) {
        na[r] = norm2[aglob0 + kg * 4 + r];
        la[r] = labA[arow0 + kg * 4 + r];
    }

    float bpv[4], bnv[4]; int bpj[4], bnj[4];
    #pragma unroll
    for (int r = 0; r < 4; ++r) { bpv[r] = -1.0f; bpj[r] = 0x7fffffff; bnv[r] = FLT_MAX; bnj[r] = 0x7fffffff; }

    #pragma unroll
    for (int s = 0; s < 8; ++s) {
        #pragma unroll
        for (int r = 0; r < 4; ++r) {
            const float d2 = fmaxf(na[r] + nb[s] - 2.0f * acc[s][r], 0.0f);
            const bool same = (la[r] == lb[s]);
            const float pv = same ? d2 : 0.0f;
            const float nv = same ? FLT_MAX : d2;
            // jcol ascending in s -> strict compares keep first occurrence
            if (pv > bpv[r]) { bpv[r] = pv; bpj[r] = jcol[s]; }
            if (nv < bnv[r]) { bnv[r] = nv; bnj[r] = jcol[s]; }
        }
    }

    // reduce across the 16 lanes of each row group (masks < 16 keep kg fixed)
    #pragma unroll
    for (int r = 0; r < 4; ++r) {
        #pragma unroll
        for (int m = 8; m > 0; m >>= 1) {
            const float opv = __shfl_xor(bpv[r], m); const int opj = __shfl_xor(bpj[r], m);
            if (opv > bpv[r] || (opv == bpv[r] && opj < bpj[r])) { bpv[r] = opv; bpj[r] = opj; }
            const float onv = __shfl_xor(bnv[r], m); const int onj = __shfl_xor(bnj[r], m);
            if (onv < bnv[r] || (onv == bnv[r] && onj < bnj[r])) { bnv[r] = onv; bnj[r] = onj; }
        }
    }

    // ---- cross-wave combine: 16 rows x 8 col-chunks ----
    __shared__ float L_pv[16][8]; __shared__ int L_pj[16][8];
    __shared__ float L_nv[16][8]; __shared__ int L_nj[16][8];
    if (l15 == 0) {
        #pragma unroll
        for (int r = 0; r < 4; ++r) {
            const int rib = kg * 4 + r;
            L_pv[rib][w] = bpv[r]; L_pj[rib][w] = bpj[r];
            L_nv[rib][w] = bnv[r]; L_nj[rib][w] = bnj[r];
        }
    }
    __syncthreads();

    __shared__ int s_pp[16], s_pn[16];
    __shared__ float s_fp[16], s_cn[16];
    if (t < 16) {
        float pv = -1.0f; int pj = 0x7fffffff; float nv = FLT_MAX; int nj = 0x7fffffff;
        #pragma unroll
        for (int c = 0; c < 8; ++c) {   // ascending col ranges -> tie keeps first
            const float v1 = L_pv[t][c]; const int j1 = L_pj[t][c];
            if (v1 > pv || (v1 == pv && j1 < pj)) { pv = v1; pj = j1; }
            const float v2 = L_nv[t][c]; const int j2 = L_nj[t][c];
            if (v2 < nv || (v2 == nv && j2 < nj)) { nv = v2; nj = j2; }
        }
        s_pp[t] = pj > (BATCH - 1) ? (BATCH - 1) : pj;
        s_pn[t] = nj > (BATCH - 1) ? (BATCH - 1) : nj;
        s_fp[t] = (pv > 0.0f) ? sqrtf(pv + EPSV) : 0.0f;   // no-positive row -> 0
        s_cn[t] = sqrtf(nv + EPSV);
    }
    __syncthreads();

    // ---- intra distances (exact fp32): 16 rows x 16 lanes ----
    __shared__ float ls[16];
    if (t < 256) {
        const int g = t >> 4, sl = t & 15;
        const float* fb = feat + (half ? 0 : BATCH * DIM);   // b-side = f_intra
        const float4* x = reinterpret_cast<const float4*>(fb + (size_t)s_pp[g] * DIM + sl * 8);
        const float4* y = reinterpret_cast<const float4*>(fb + (size_t)s_pn[g] * DIM + sl * 8);
        const float4 x0 = x[0], x1 = x[1], y0 = y[0], y1 = y[1];
        float d, d2;
        d = x0.x - y0.x; d2  = d * d;  d = x0.y - y0.y; d2 += d * d;
        d = x0.z - y0.z; d2 += d * d;  d = x0.w - y0.w; d2 += d * d;
        d = x1.x - y1.x; d2 += d * d;  d = x1.y - y1.y; d2 += d * d;
        d = x1.z - y1.z; d2 += d * d;  d = x1.w - y1.w; d2 += d * d;
        d2 += __shfl_xor(d2, 1); d2 += __shfl_xor(d2, 2);
        d2 += __shfl_xor(d2, 4); d2 += __shfl_xor(d2, 8);
        if (sl == 0) {
            const float gd = sqrtf(d2 + EPSV);
            const float loss = fmaxf(s_fp[g] - s_cn[g] + MARGIN, 0.0f)
                             + LAMDA * fmaxf(INTRA_MARGIN - gd, 0.0f);
            ls[g] = loss * (1.0f / (float)BATCH);
        }
    }
    __syncthreads();

    // ---- per-block partial + last-block deterministic final sum ----
    if (t == 0) {
        float s = 0.0f;
        #pragma unroll
        for (int i = 0; i < 16; ++i) s += ls[i];
        partial[bid] = s;
        __threadfence();
        const unsigned int old = atomicAdd(counter, 1u);
        if (old == 127u) {
            __threadfence();
            float tot = 0.0f;
            for (int i = 0; i < 128; ++i) tot += partial[i];   // fixed order -> deterministic
            out[0] = tot;
        }
    }
}

extern "C" void kernel_launch(void* const* d_in, const int* in_sizes, int n_in,
                              void* d_out, int out_size, void* d_ws, size_t ws_size,
                              hipStream_t stream) {
    const float* feat   = (const float*)d_in[0];
    const int*   label1 = (const int*)d_in[1];
    const int*   label2 = (const int*)d_in[2];
    float* out = (float*)d_out;

    char* ws = (char*)d_ws;
    ushort*       bhi     = (ushort*)(ws);                    // 512 KB
    float*        norm2   = (float*)(ws + 512 * 1024);        // 8 KB
    float*        partial = (float*)(ws + 528 * 1024);        // 512 B
    unsigned int* counter = (unsigned int*)(ws + 532 * 1024); // 4 B

    prep_kernel<<<dim3(128), dim3(256), 0, stream>>>(feat, bhi, norm2, counter);
    gemm_finalize_kernel<<<dim3(128), dim3(512), 0, stream>>>(
        bhi, norm2, feat, label1, label2, partial, counter, out);
}